// Round 17
// baseline (514.067 us; speedup 1.0000x reference)
//
#include <hip/hip_runtime.h>

#define IC 4096
typedef unsigned short u16;
typedef unsigned int   u32;
typedef __fp16 h2 __attribute__((ext_vector_type(2)));   // cvt_pkrtz return type

static __device__ __forceinline__ u32 pack_rtz(float a, float b) {
    h2 h = __builtin_amdgcn_cvt_pkrtz(a, b);   // v_cvt_pkrtz_f16_f32
    u32 u; __builtin_memcpy(&u, &h, 4); return u;
}
static __device__ __forceinline__ float h2lo(u32 r) {
    h2 h; __builtin_memcpy(&h, &r, 4); return (float)h.x;
}
static __device__ __forceinline__ float h2hi(u32 r) {
    h2 h; __builtin_memcpy(&h, &r, 4); return (float)h.y;
}

// Barrier that drains only lgkmcnt (LDS/scalar), not vmcnt (r16, proven safe).
static __device__ __forceinline__ void barrier_lgkm() {
    asm volatile("s_waitcnt lgkmcnt(0)\n\ts_barrier" ::: "memory");
}

// ---------------- primary path: 256-thread blocks, 2 i per wave ----------
// Diagnosis r8-r16: per-phase critical path (~2000 cyc of load/LDS/barrier
// latency) with only ~2.7 resident 512-thread blocks per CU to interleave.
// Fix: 256-thread blocks (8 blocks/CU by thread cap = 3x the independent
// phase-machines) and each wave owns TWO i, accumulating cw*u over both in
// registers before one LDS write (phase machinery amortized 2x). Math,
// partial layout, and squash are identical to r13 (absmax 3.9e-3).
template<int USEV>
__global__ __launch_bounds__(256)
void caps_pass_part(const float* __restrict__ x, const float* __restrict__ W,
                    const float* __restrict__ vprev, u32* __restrict__ part)
{
    __shared__ float lds[4][4][256];   // [wave][nb][a*16+d] = 16 KB
    const int tid  = threadIdx.x;      // 0..255
    const int wu   = __builtin_amdgcn_readfirstlane(tid >> 6);  // wave 0..3
    const int lane = tid & 63;
    const int a    = lane >> 2;   // capsule 0..15
    const int dq   = lane & 3;    // d-quad: lane owns d = dq*4..dq*4+3
    const int ib   = (int)blockIdx.x & 511;   // i-chunk (8 i)
    const int bh   = (int)blockIdx.x >> 9;    // b-half
    const int i0   = ib * 8 + wu * 2;         // this wave's two i
    const int b0   = bh * 128;
    const float SM_SCALE = 4096.0f * 1.44269504088896f;  // logits in log2 units

    // W slices for the wave's two i (compiler may remat; that's the measured
    // cheap L1 stream from r13 -- do not fight it)
    float w[2][32];
#pragma unroll
    for (int ii = 0; ii < 2; ++ii) {
        const float* wp = W + ((size_t)a * IC + (i0 + ii)) * 128 + dq * 32;
#pragma unroll
        for (int q = 0; q < 8; ++q) {
            const float4 f = *(const float4*)(wp + q * 4);
            w[ii][q*4+0] = f.x; w[ii][q*4+1] = f.y;
            w[ii][q*4+2] = f.z; w[ii][q*4+3] = f.w;
        }
    }
#pragma unroll
    for (int ii = 0; ii < 2; ++ii)
#pragma unroll
        for (int k = 0; k < 32; ++k) asm volatile("" : "+v"(w[ii][k]));

    for (int ph = 0; ph < 32; ++ph) {
        // prefetch the 4 b's inputs for both i (x is wave-uniform)
        float4 xa[4][2], xb[4][2], va[4];
#pragma unroll
        for (int nb = 0; nb < 4; ++nb) {
            const int b = b0 + ph * 4 + nb;
#pragma unroll
            for (int ii = 0; ii < 2; ++ii) {
                const float* xp = x + ((size_t)b * IC + (i0 + ii)) * 8;
                xa[nb][ii] = *(const float4*)(xp);
                xb[nb][ii] = *(const float4*)(xp + 4);
            }
            if (USEV)
                va[nb] = *(const float4*)(vprev + (((size_t)b * 16 + a) * 16 + dq * 4));
        }
#pragma unroll
        for (int nb = 0; nb < 4; ++nb) {
            float s0 = 0.f, s1 = 0.f, s2 = 0.f, s3 = 0.f;  // sum over 2 i
#pragma unroll
            for (int ii = 0; ii < 2; ++ii) {
                float u0, u1, u2, u3;
                u0 = xa[nb][ii].x * w[ii][0];
                u1 = xa[nb][ii].x * w[ii][8];
                u2 = xa[nb][ii].x * w[ii][16];
                u3 = xa[nb][ii].x * w[ii][24];
                u0 = fmaf(xa[nb][ii].y, w[ii][1],  u0); u1 = fmaf(xa[nb][ii].y, w[ii][9],  u1);
                u2 = fmaf(xa[nb][ii].y, w[ii][17], u2); u3 = fmaf(xa[nb][ii].y, w[ii][25], u3);
                u0 = fmaf(xa[nb][ii].z, w[ii][2],  u0); u1 = fmaf(xa[nb][ii].z, w[ii][10], u1);
                u2 = fmaf(xa[nb][ii].z, w[ii][18], u2); u3 = fmaf(xa[nb][ii].z, w[ii][26], u3);
                u0 = fmaf(xa[nb][ii].w, w[ii][3],  u0); u1 = fmaf(xa[nb][ii].w, w[ii][11], u1);
                u2 = fmaf(xa[nb][ii].w, w[ii][19], u2); u3 = fmaf(xa[nb][ii].w, w[ii][27], u3);
                u0 = fmaf(xb[nb][ii].x, w[ii][4],  u0); u1 = fmaf(xb[nb][ii].x, w[ii][12], u1);
                u2 = fmaf(xb[nb][ii].x, w[ii][20], u2); u3 = fmaf(xb[nb][ii].x, w[ii][28], u3);
                u0 = fmaf(xb[nb][ii].y, w[ii][5],  u0); u1 = fmaf(xb[nb][ii].y, w[ii][13], u1);
                u2 = fmaf(xb[nb][ii].y, w[ii][21], u2); u3 = fmaf(xb[nb][ii].y, w[ii][29], u3);
                u0 = fmaf(xb[nb][ii].z, w[ii][6],  u0); u1 = fmaf(xb[nb][ii].z, w[ii][14], u1);
                u2 = fmaf(xb[nb][ii].z, w[ii][22], u2); u3 = fmaf(xb[nb][ii].z, w[ii][30], u3);
                u0 = fmaf(xb[nb][ii].w, w[ii][7],  u0); u1 = fmaf(xb[nb][ii].w, w[ii][15], u1);
                u2 = fmaf(xb[nb][ii].w, w[ii][23], u2); u3 = fmaf(xb[nb][ii].w, w[ii][31], u3);
                float cw;
                if (USEV == 0) {
                    cw = 1.0f / 16.0f;
                } else {
                    // agree = u . vprev  (vprev = v1, or v1+v2 for last pass)
                    float ag = u0 * va[nb].x + u1 * va[nb].y
                             + u2 * va[nb].z + u3 * va[nb].w;
                    ag += __shfl_xor(ag, 1);   // combine d-quads in the a-group
                    ag += __shfl_xor(ag, 2);
                    const float blog2 = SM_SCALE * ag;
                    // softmax over 16 capsules (4-lane groups); strides 4..32
                    // keep lane bits 0-1 fixed -> replicas fold once per a.
                    float m = blog2;
                    m = fmaxf(m, __shfl_xor(m, 4));
                    m = fmaxf(m, __shfl_xor(m, 8));
                    m = fmaxf(m, __shfl_xor(m, 16));
                    m = fmaxf(m, __shfl_xor(m, 32));
                    const float e = __builtin_amdgcn_exp2f(blog2 - m);
                    float sum = e;
                    sum += __shfl_xor(sum, 4);
                    sum += __shfl_xor(sum, 8);
                    sum += __shfl_xor(sum, 16);
                    sum += __shfl_xor(sum, 32);
                    cw = __fdividef(e, sum);
                }
                s0 = fmaf(cw, u0, s0);
                s1 = fmaf(cw, u1, s1);
                s2 = fmaf(cw, u2, s2);
                s3 = fmaf(cw, u3, s3);
            }
            // one LDS write per (b, wave): both i already summed in registers
            *(float4*)&lds[wu][nb][lane * 4] = make_float4(s0, s1, s2, s3);
        }
        barrier_lgkm();
        // reduce: 256 threads; thread = (nb = tid>>6, col4 = tid&63).
        // float4 over 4 waves, single fp16 RTZ rounding at the global store.
        {
            const int nb   = tid >> 6;    // 0..3
            const int col4 = tid & 63;    // float4 column
            float4 acc = make_float4(0.f, 0.f, 0.f, 0.f);
#pragma unroll
            for (int wv = 0; wv < 4; ++wv) {
                const float4 f = *(const float4*)&lds[wv][nb][col4 * 4];
                acc.x += f.x; acc.y += f.y; acc.z += f.z; acc.w += f.w;
            }
            const u32 p0 = pack_rtz(acc.x, acc.y);
            const u32 p1 = pack_rtz(acc.z, acc.w);
            *(uint2*)&part[(size_t)blockIdx.x * 16384
                           + (size_t)(ph * 4 + nb) * 128 + col4 * 2] =
                make_uint2(p0, p1);
        }
        barrier_lgkm();
    }
}

// Fused 512-deep partial reduction + squash. Thread = (b, a, d-pair):
// 32768 threads; d-norm via shfl_xor over the 8 d-pair lanes.
template<int ADDP>
__global__ __launch_bounds__(256)
void caps_squash_part(const u32* __restrict__ part, float* __restrict__ vout,
                      const float* __restrict__ vprev)
{
    const int gt = (int)blockIdx.x * 256 + (int)threadIdx.x;  // 0..32767
    const int b  = gt >> 7;
    const int r  = gt & 127;                                  // a*8 + dpair
    const int h  = b >> 7;                                    // b-half
    const int lb = b & 127;                                   // local b in tile
    const u32* pp = part + ((size_t)h * 512) * 16384 + (size_t)lb * 128 + r;
    float f0 = 0.f, f1 = 0.f;
#pragma unroll 8
    for (int ic = 0; ic < 512; ++ic) {
        const u32 raw = pp[(size_t)ic * 16384];
        f0 += h2lo(raw);
        f1 += h2hi(raw);
    }
    float sq = f0 * f0 + f1 * f1;
    sq += __shfl_xor(sq, 1);
    sq += __shfl_xor(sq, 2);
    sq += __shfl_xor(sq, 4);
    const float scale = sq / ((1.0f + sq) * sqrtf(sq + 1e-7f));
    float o0 = f0 * scale, o1 = f1 * scale;
    if (ADDP) {
        const float2 p = *(const float2*)(vprev + (size_t)b * 256 + r * 2);
        o0 += p.x; o1 += p.y;
    }
    *(float2*)(vout + (size_t)b * 256 + r * 2) = make_float2(o0, o1);
}

// ---------------- legacy fallback (round-4, known-good) ----------------
template<int USEV>
__global__ __launch_bounds__(512)
void legacy_pass(const float* __restrict__ x, const float* __restrict__ W,
                 const float* __restrict__ vprev, float* __restrict__ s_rep,
                 int n_rep)
{
    __shared__ float lds[8][4][256];
    const int tid  = threadIdx.x;
    const int wu   = __builtin_amdgcn_readfirstlane(tid >> 6);
    const int lane = tid & 63;
    const int a    = lane >> 2;
    const int dq   = lane & 3;
    const int ichunk = (int)blockIdx.x >> 1;
    const int bhalf  = (int)blockIdx.x & 1;
    const int i0 = ichunk * 32 + wu * 4;
    const int rep = (int)blockIdx.x & (n_rep - 1);
    float* srep = s_rep + (size_t)rep * 65536;

    float w[4][32];
#pragma unroll
    for (int ii = 0; ii < 4; ++ii) {
        const float* wp = W + ((size_t)a * IC + (size_t)(i0 + ii)) * 128 + dq * 32;
#pragma unroll
        for (int q = 0; q < 8; ++q) {
            const float4 f = *(const float4*)(wp + q * 4);
            w[ii][q*4+0]=f.x; w[ii][q*4+1]=f.y; w[ii][q*4+2]=f.z; w[ii][q*4+3]=f.w;
        }
    }
#pragma unroll
    for (int ii = 0; ii < 4; ++ii)
#pragma unroll
        for (int k = 0; k < 32; ++k) asm volatile("" : "+v"(w[ii][k]));

    const int b0 = bhalf * 128;
    for (int ph = 0; ph < 32; ++ph) {
        float sl[4][4];
#pragma unroll
        for (int nb = 0; nb < 4; ++nb) {
            sl[nb][0]=0.f; sl[nb][1]=0.f; sl[nb][2]=0.f; sl[nb][3]=0.f;
            const int b = b0 + ph * 4 + nb;
            float4 va;
            if (USEV)
                va = *(const float4*)(vprev + (((size_t)b * 16 + a) * 16 + dq * 4));
#pragma unroll
            for (int ii = 0; ii < 4; ++ii) {
                const float* xp = x + ((size_t)b * IC + (size_t)(i0 + ii)) * 8;
                const float4 xa = *(const float4*)(xp);
                const float4 xb = *(const float4*)(xp + 4);
                float u0, u1, u2, u3;
                u0 = xa.x * w[ii][0];  u1 = xa.x * w[ii][8];
                u2 = xa.x * w[ii][16]; u3 = xa.x * w[ii][24];
                u0 = fmaf(xa.y, w[ii][1],  u0); u1 = fmaf(xa.y, w[ii][9],  u1);
                u2 = fmaf(xa.y, w[ii][17], u2); u3 = fmaf(xa.y, w[ii][25], u3);
                u0 = fmaf(xa.z, w[ii][2],  u0); u1 = fmaf(xa.z, w[ii][10], u1);
                u2 = fmaf(xa.z, w[ii][18], u2); u3 = fmaf(xa.z, w[ii][26], u3);
                u0 = fmaf(xa.w, w[ii][3],  u0); u1 = fmaf(xa.w, w[ii][11], u1);
                u2 = fmaf(xa.w, w[ii][19], u2); u3 = fmaf(xa.w, w[ii][27], u3);
                u0 = fmaf(xb.x, w[ii][4],  u0); u1 = fmaf(xb.x, w[ii][12], u1);
                u2 = fmaf(xb.x, w[ii][20], u2); u3 = fmaf(xb.x, w[ii][28], u3);
                u0 = fmaf(xb.y, w[ii][5],  u0); u1 = fmaf(xb.y, w[ii][13], u1);
                u2 = fmaf(xb.y, w[ii][21], u2); u3 = fmaf(xb.y, w[ii][29], u3);
                u0 = fmaf(xb.z, w[ii][6],  u0); u1 = fmaf(xb.z, w[ii][14], u1);
                u2 = fmaf(xb.z, w[ii][22], u2); u3 = fmaf(xb.z, w[ii][30], u3);
                u0 = fmaf(xb.w, w[ii][7],  u0); u1 = fmaf(xb.w, w[ii][15], u1);
                u2 = fmaf(xb.w, w[ii][23], u2); u3 = fmaf(xb.w, w[ii][31], u3);
                float cw;
                if (USEV == 0) {
                    cw = 1.0f / 16.0f;
                } else {
                    float ag = u0*va.x + u1*va.y + u2*va.z + u3*va.w;
                    ag += __shfl_xor(ag, 1);
                    ag += __shfl_xor(ag, 2);
                    const float blog = 4096.0f * ag;
                    float m = blog;
                    m = fmaxf(m, __shfl_xor(m, 4));
                    m = fmaxf(m, __shfl_xor(m, 8));
                    m = fmaxf(m, __shfl_xor(m, 16));
                    m = fmaxf(m, __shfl_xor(m, 32));
                    const float e = __expf(blog - m);
                    float sum = e;
                    sum += __shfl_xor(sum, 4);
                    sum += __shfl_xor(sum, 8);
                    sum += __shfl_xor(sum, 16);
                    sum += __shfl_xor(sum, 32);
                    cw = __fdividef(e, sum);
                }
                sl[nb][0] = fmaf(cw, u0, sl[nb][0]);
                sl[nb][1] = fmaf(cw, u1, sl[nb][1]);
                sl[nb][2] = fmaf(cw, u2, sl[nb][2]);
                sl[nb][3] = fmaf(cw, u3, sl[nb][3]);
            }
        }
#pragma unroll
        for (int nb = 0; nb < 4; ++nb)
            *(float4*)&lds[wu][nb][lane * 4] =
                make_float4(sl[nb][0], sl[nb][1], sl[nb][2], sl[nb][3]);
        __syncthreads();
        if (tid < 256) {
            const int bsel = tid >> 6;
            const int ad4  = (tid & 63) * 4;
            float4 acc = make_float4(0.f, 0.f, 0.f, 0.f);
#pragma unroll
            for (int wv = 0; wv < 8; ++wv) {
                const float4 f = *(const float4*)&lds[wv][bsel][ad4];
                acc.x += f.x; acc.y += f.y; acc.z += f.z; acc.w += f.w;
            }
            float* dst = srep + (size_t)(b0 + ph * 4 + bsel) * 256 + ad4;
            unsafeAtomicAdd(dst + 0, acc.x);
            unsafeAtomicAdd(dst + 1, acc.y);
            unsafeAtomicAdd(dst + 2, acc.z);
            unsafeAtomicAdd(dst + 3, acc.w);
        }
        __syncthreads();
    }
}

template<int ADDP, int ZERO>
__global__ void legacy_squash(float* __restrict__ srep, int n_rep,
                              float* __restrict__ vout, const float* __restrict__ vprev)
{
    const int t = (int)blockIdx.x * 256 + (int)threadIdx.x;
    float4 f0 = make_float4(0.f,0.f,0.f,0.f), f1 = f0, f2 = f0, f3 = f0;
    for (int r = 0; r < n_rep; ++r) {
        float* sp = srep + (size_t)r * 65536 + (size_t)t * 16;
        const float4 a0 = *(const float4*)(sp + 0);
        const float4 a1 = *(const float4*)(sp + 4);
        const float4 a2 = *(const float4*)(sp + 8);
        const float4 a3 = *(const float4*)(sp + 12);
        f0.x+=a0.x; f0.y+=a0.y; f0.z+=a0.z; f0.w+=a0.w;
        f1.x+=a1.x; f1.y+=a1.y; f1.z+=a1.z; f1.w+=a1.w;
        f2.x+=a2.x; f2.y+=a2.y; f2.z+=a2.z; f2.w+=a2.w;
        f3.x+=a3.x; f3.y+=a3.y; f3.z+=a3.z; f3.w+=a3.w;
        if (ZERO) {
            const float4 z = make_float4(0.f,0.f,0.f,0.f);
            *(float4*)(sp+0)=z; *(float4*)(sp+4)=z; *(float4*)(sp+8)=z; *(float4*)(sp+12)=z;
        }
    }
    float sq = f0.x*f0.x+f0.y*f0.y+f0.z*f0.z+f0.w*f0.w
             + f1.x*f1.x+f1.y*f1.y+f1.z*f1.z+f1.w*f1.w
             + f2.x*f2.x+f2.y*f2.y+f2.z*f2.z+f2.w*f2.w
             + f3.x*f3.x+f3.y*f3.y+f3.z*f3.z+f3.w*f3.w;
    const float scale = sq / ((1.0f + sq) * sqrtf(sq + 1e-7f));
    float4 o0, o1, o2, o3;
    o0.x=f0.x*scale; o0.y=f0.y*scale; o0.z=f0.z*scale; o0.w=f0.w*scale;
    o1.x=f1.x*scale; o1.y=f1.y*scale; o1.z=f1.z*scale; o1.w=f1.w*scale;
    o2.x=f2.x*scale; o2.y=f2.y*scale; o2.z=f2.z*scale; o2.w=f2.w*scale;
    o3.x=f3.x*scale; o3.y=f3.y*scale; o3.z=f3.z*scale; o3.w=f3.w*scale;
    if (ADDP) {
        const float* pp = vprev + (size_t)t * 16;
        const float4 p0 = *(const float4*)(pp + 0);
        const float4 p1 = *(const float4*)(pp + 4);
        const float4 p2 = *(const float4*)(pp + 8);
        const float4 p3 = *(const float4*)(pp + 12);
        o0.x+=p0.x; o0.y+=p0.y; o0.z+=p0.z; o0.w+=p0.w;
        o1.x+=p1.x; o1.y+=p1.y; o1.z+=p1.z; o1.w+=p1.w;
        o2.x+=p2.x; o2.y+=p2.y; o2.z+=p2.z; o2.w+=p2.w;
        o3.x+=p3.x; o3.y+=p3.y; o3.z+=p3.z; o3.w+=p3.w;
    }
    float* vp = vout + (size_t)t * 16;
    *(float4*)(vp+0)=o0; *(float4*)(vp+4)=o1; *(float4*)(vp+8)=o2; *(float4*)(vp+12)=o3;
}

__global__ void legacy_zero(float* __restrict__ p)
{
    *(float4*)(p + ((size_t)blockIdx.x * 256 + threadIdx.x) * 4) =
        make_float4(0.f, 0.f, 0.f, 0.f);
}

extern "C" void kernel_launch(void* const* d_in, const int* in_sizes, int n_in,
                              void* d_out, int out_size, void* d_ws, size_t ws_size,
                              hipStream_t stream)
{
    const float* x = (const float*)d_in[0];   // [256, 4096, 8]
    const float* W = (const float*)d_in[1];   // [16, 4096, 16, 8]
    float* out = (float*)d_out;               // [256, 16, 16]

    // fp16 partials: 1024 tiles x 16384 u32 = 64 MiB
    const size_t need16 = (size_t)1024 * 16384 * 4 + 2 * 65536 * 4;

    if (ws_size >= need16) {
        u32*  part = (u32*)d_ws;
        float* v1  = (float*)((char*)d_ws + (size_t)1024 * 16384 * 4);
        float* vs  = v1 + 65536;
        caps_pass_part<0><<<1024, 256, 0, stream>>>(x, W, nullptr, part);
        caps_squash_part<0><<<128, 256, 0, stream>>>(part, v1, nullptr);
        caps_pass_part<1><<<1024, 256, 0, stream>>>(x, W, v1, part);
        caps_squash_part<1><<<128, 256, 0, stream>>>(part, vs, v1);
        caps_pass_part<1><<<1024, 256, 0, stream>>>(x, W, vs, part);
        caps_squash_part<0><<<128, 256, 0, stream>>>(part, out, nullptr);
    } else {
        int R = 1;
        if (ws_size >= (size_t)(8 + 2) * 65536 * 4) R = 8;
        else if (ws_size >= (size_t)(2 + 2) * 65536 * 4) R = 2;
        float* srep = (float*)d_ws;
        float* v1   = srep + (size_t)R * 65536;
        float* vs   = v1 + 65536;
        legacy_zero<<<R * 64, 256, 0, stream>>>(srep);
        legacy_pass<0><<<256, 512, 0, stream>>>(x, W, nullptr, srep, R);
        legacy_squash<0, 1><<<16, 256, 0, stream>>>(srep, R, v1, nullptr);
        legacy_pass<1><<<256, 512, 0, stream>>>(x, W, v1, srep, R);
        legacy_squash<1, 1><<<16, 256, 0, stream>>>(srep, R, vs, v1);
        legacy_pass<1><<<256, 512, 0, stream>>>(x, W, vs, srep, R);
        legacy_squash<0, 0><<<16, 256, 0, stream>>>(srep, R, out, nullptr);
    }
}

// Round 18
// 497.672 us; speedup vs baseline: 1.0329x; 1.0329x over previous
//
#include <hip/hip_runtime.h>

#define IC 4096
typedef unsigned short u16;
typedef unsigned int   u32;
typedef __fp16 h2 __attribute__((ext_vector_type(2)));   // cvt_pkrtz return type

static __device__ __forceinline__ u32 pack_rtz(float a, float b) {
    h2 h = __builtin_amdgcn_cvt_pkrtz(a, b);   // v_cvt_pkrtz_f16_f32
    u32 u; __builtin_memcpy(&u, &h, 4); return u;
}
static __device__ __forceinline__ float h2lo(u32 r) {
    h2 h; __builtin_memcpy(&h, &r, 4); return (float)h.x;
}
static __device__ __forceinline__ float h2hi(u32 r) {
    h2 h; __builtin_memcpy(&h, &r, 4); return (float)h.y;
}

// Barrier draining only lgkmcnt (r16: proven safe & neutral).
static __device__ __forceinline__ void barrier_lgkm() {
    asm volatile("s_waitcnt lgkmcnt(0)\n\ts_barrier" ::: "memory");
}

// DPP lane permute on the VALU pipe (NOT ds_bpermute/DS pipe).
// CTRL: 0xB1 = quad_perm{1,0,3,2} (xor1), 0x4E = quad_perm{2,3,0,1} (xor2),
// 0x124 = row_ror:4, 0x128 = row_ror:8 (row = 16 lanes).
template<int CTRL>
static __device__ __forceinline__ float dppf(float x) {
    return __int_as_float(__builtin_amdgcn_update_dpp(
        0, __float_as_int(x), CTRL, 0xF, 0xF, true));
}

// ---------------- primary path: DPP softmax (DS-pipe relief) ----------
// Diagnosis r8-r17: the 10 ds_bpermute per (b,i) (__shfl_xor softmax) put
// ~140us/pass on the DS pipe -- co-bottleneck with VALU at 54%. Remap
// a = lane&15, dq = lane>>4 so the 16-capsule softmax reduce lives within
// 16-lane rows: quad_perm xor1/xor2 + row_ror 4/8 -- all VALU DPP, zero DS.
// Only ag's dq-combine (strides 16, 32) stays on DS (2 ops vs 10).
// Skeleton, partial layout, and squash identical to r13 (absmax 3.9e-3).
template<int USEV>
__global__ __launch_bounds__(512)
void caps_pass_part(const float* __restrict__ x, const float* __restrict__ W,
                    const float* __restrict__ vprev, u32* __restrict__ part)
{
    __shared__ float lds[8][4][256];
    const int tid  = threadIdx.x;
    const int wu   = __builtin_amdgcn_readfirstlane(tid >> 6);  // wave 0..7
    const int lane = tid & 63;
    const int a    = lane & 15;   // capsule 0..15  (row-of-16 position)
    const int dq   = lane >> 4;   // d-quad 0..3: lane owns d = dq*4..dq*4+3
    const int ib   = (int)blockIdx.x & 511;   // i-chunk
    const int bh   = (int)blockIdx.x >> 9;    // b-half
    const int i    = ib * 8 + wu;             // this wave's i

    float w[32];
    {
        const float* wp = W + ((size_t)a * IC + i) * 128 + dq * 32;
#pragma unroll
        for (int q = 0; q < 8; ++q) {
            const float4 f = *(const float4*)(wp + q * 4);
            w[q*4+0] = f.x; w[q*4+1] = f.y; w[q*4+2] = f.z; w[q*4+3] = f.w;
        }
    }
#pragma unroll
    for (int k = 0; k < 32; ++k) asm volatile("" : "+v"(w[k]));  // no remat

    const int b0 = bh * 128;
    const float SM_SCALE = 4096.0f * 1.44269504088896f;  // logits in log2 units

    for (int ph = 0; ph < 32; ++ph) {
        // prefetch all 4 b's inputs (independent; x is wave-uniform)
        float4 xa[4], xb[4], va[4];
#pragma unroll
        for (int nb = 0; nb < 4; ++nb) {
            const int b = b0 + ph * 4 + nb;
            const float* xp = x + ((size_t)b * IC + i) * 8;
            xa[nb] = *(const float4*)(xp);
            xb[nb] = *(const float4*)(xp + 4);
            if (USEV)
                va[nb] = *(const float4*)(vprev + (((size_t)b * 16 + a) * 16 + dq * 4));
        }
#pragma unroll
        for (int nb = 0; nb < 4; ++nb) {
            float u0, u1, u2, u3;
            u0 = xa[nb].x * w[0];
            u1 = xa[nb].x * w[8];
            u2 = xa[nb].x * w[16];
            u3 = xa[nb].x * w[24];
            u0 = fmaf(xa[nb].y, w[1],  u0); u1 = fmaf(xa[nb].y, w[9],  u1);
            u2 = fmaf(xa[nb].y, w[17], u2); u3 = fmaf(xa[nb].y, w[25], u3);
            u0 = fmaf(xa[nb].z, w[2],  u0); u1 = fmaf(xa[nb].z, w[10], u1);
            u2 = fmaf(xa[nb].z, w[18], u2); u3 = fmaf(xa[nb].z, w[26], u3);
            u0 = fmaf(xa[nb].w, w[3],  u0); u1 = fmaf(xa[nb].w, w[11], u1);
            u2 = fmaf(xa[nb].w, w[19], u2); u3 = fmaf(xa[nb].w, w[27], u3);
            u0 = fmaf(xb[nb].x, w[4],  u0); u1 = fmaf(xb[nb].x, w[12], u1);
            u2 = fmaf(xb[nb].x, w[20], u2); u3 = fmaf(xb[nb].x, w[28], u3);
            u0 = fmaf(xb[nb].y, w[5],  u0); u1 = fmaf(xb[nb].y, w[13], u1);
            u2 = fmaf(xb[nb].y, w[21], u2); u3 = fmaf(xb[nb].y, w[29], u3);
            u0 = fmaf(xb[nb].z, w[6],  u0); u1 = fmaf(xb[nb].z, w[14], u1);
            u2 = fmaf(xb[nb].z, w[22], u2); u3 = fmaf(xb[nb].z, w[30], u3);
            u0 = fmaf(xb[nb].w, w[7],  u0); u1 = fmaf(xb[nb].w, w[15], u1);
            u2 = fmaf(xb[nb].w, w[23], u2); u3 = fmaf(xb[nb].w, w[31], u3);
            float cw;
            if (USEV == 0) {
                cw = 1.0f / 16.0f;
            } else {
                // agree = u . vprev; combine the 4 d-quads (lanes a, a+16,
                // a+32, a+48) -- the only remaining DS ops (2 vs 10).
                float ag = u0 * va[nb].x + u1 * va[nb].y
                         + u2 * va[nb].z + u3 * va[nb].w;
                ag += __shfl_xor(ag, 16);
                ag += __shfl_xor(ag, 32);
                const float blog2 = SM_SCALE * ag;
                // softmax over the 16 capsules = reduce within the 16-lane
                // row, entirely on VALU DPP: xor1, xor2 (quad-uniform), then
                // ror4 + ror8 rotations complete the row total on every lane.
                float m = blog2;
                m = fmaxf(m, dppf<0xB1>(m));    // quad_perm xor1
                m = fmaxf(m, dppf<0x4E>(m));    // quad_perm xor2
                m = fmaxf(m, dppf<0x124>(m));   // row_ror:4
                m = fmaxf(m, dppf<0x128>(m));   // row_ror:8
                const float e = __builtin_amdgcn_exp2f(blog2 - m);
                float sum = e;
                sum += dppf<0xB1>(sum);
                sum += dppf<0x4E>(sum);
                sum += dppf<0x124>(sum);
                sum += dppf<0x128>(sum);
                cw = __fdividef(e, sum);
            }
            // linear per-lane LDS write (conflict-free); element order is now
            // dq*64 + a*4 + j -- accounted for in the reduce below.
            *(float4*)&lds[wu][nb][lane * 4] =
                make_float4(cw * u0, cw * u1, cw * u2, cw * u3);
        }
        barrier_lgkm();
        // reduce: ALL 512 threads; output u32 col = a*8 + p (d-pair p),
        // located in LDS at (p>>1)*64 + a*4 + (p&1)*2. Same part layout
        // as r13 -> squash unchanged. Single fp16 RTZ rounding at store.
        {
            const int nb  = tid >> 7;     // 0..3
            const int col = tid & 127;    // output u32 column = a*8 + p
            const int ca  = col >> 3;
            const int p   = col & 7;
            const int off = (p >> 1) * 64 + ca * 4 + (p & 1) * 2;
            float s0 = 0.f, s1 = 0.f;
#pragma unroll
            for (int wv = 0; wv < 8; ++wv) {
                const float2 f = *(const float2*)&lds[wv][nb][off];
                s0 += f.x; s1 += f.y;
            }
            part[(size_t)blockIdx.x * 16384 + (size_t)(ph * 4 + nb) * 128 + col] =
                pack_rtz(s0, s1);
        }
        barrier_lgkm();
    }
}

// Fused 512-deep partial reduction + squash. Thread = (b, a, d-pair):
// 32768 threads; d-norm via shfl_xor over the 8 d-pair lanes.
template<int ADDP>
__global__ __launch_bounds__(256)
void caps_squash_part(const u32* __restrict__ part, float* __restrict__ vout,
                      const float* __restrict__ vprev)
{
    const int gt = (int)blockIdx.x * 256 + (int)threadIdx.x;  // 0..32767
    const int b  = gt >> 7;
    const int r  = gt & 127;                                  // a*8 + dpair
    const int h  = b >> 7;                                    // b-half
    const int lb = b & 127;                                   // local b in tile
    const u32* pp = part + ((size_t)h * 512) * 16384 + (size_t)lb * 128 + r;
    float f0 = 0.f, f1 = 0.f;
#pragma unroll 8
    for (int ic = 0; ic < 512; ++ic) {
        const u32 raw = pp[(size_t)ic * 16384];
        f0 += h2lo(raw);
        f1 += h2hi(raw);
    }
    float sq = f0 * f0 + f1 * f1;
    sq += __shfl_xor(sq, 1);
    sq += __shfl_xor(sq, 2);
    sq += __shfl_xor(sq, 4);
    const float scale = sq / ((1.0f + sq) * sqrtf(sq + 1e-7f));
    float o0 = f0 * scale, o1 = f1 * scale;
    if (ADDP) {
        const float2 p = *(const float2*)(vprev + (size_t)b * 256 + r * 2);
        o0 += p.x; o1 += p.y;
    }
    *(float2*)(vout + (size_t)b * 256 + r * 2) = make_float2(o0, o1);
}

// ---------------- legacy fallback (round-4, known-good) ----------------
template<int USEV>
__global__ __launch_bounds__(512)
void legacy_pass(const float* __restrict__ x, const float* __restrict__ W,
                 const float* __restrict__ vprev, float* __restrict__ s_rep,
                 int n_rep)
{
    __shared__ float lds[8][4][256];
    const int tid  = threadIdx.x;
    const int wu   = __builtin_amdgcn_readfirstlane(tid >> 6);
    const int lane = tid & 63;
    const int a    = lane >> 2;
    const int dq   = lane & 3;
    const int ichunk = (int)blockIdx.x >> 1;
    const int bhalf  = (int)blockIdx.x & 1;
    const int i0 = ichunk * 32 + wu * 4;
    const int rep = (int)blockIdx.x & (n_rep - 1);
    float* srep = s_rep + (size_t)rep * 65536;

    float w[4][32];
#pragma unroll
    for (int ii = 0; ii < 4; ++ii) {
        const float* wp = W + ((size_t)a * IC + (size_t)(i0 + ii)) * 128 + dq * 32;
#pragma unroll
        for (int q = 0; q < 8; ++q) {
            const float4 f = *(const float4*)(wp + q * 4);
            w[ii][q*4+0]=f.x; w[ii][q*4+1]=f.y; w[ii][q*4+2]=f.z; w[ii][q*4+3]=f.w;
        }
    }
#pragma unroll
    for (int ii = 0; ii < 4; ++ii)
#pragma unroll
        for (int k = 0; k < 32; ++k) asm volatile("" : "+v"(w[ii][k]));

    const int b0 = bhalf * 128;
    for (int ph = 0; ph < 32; ++ph) {
        float sl[4][4];
#pragma unroll
        for (int nb = 0; nb < 4; ++nb) {
            sl[nb][0]=0.f; sl[nb][1]=0.f; sl[nb][2]=0.f; sl[nb][3]=0.f;
            const int b = b0 + ph * 4 + nb;
            float4 va;
            if (USEV)
                va = *(const float4*)(vprev + (((size_t)b * 16 + a) * 16 + dq * 4));
#pragma unroll
            for (int ii = 0; ii < 4; ++ii) {
                const float* xp = x + ((size_t)b * IC + (size_t)(i0 + ii)) * 8;
                const float4 xa = *(const float4*)(xp);
                const float4 xb = *(const float4*)(xp + 4);
                float u0, u1, u2, u3;
                u0 = xa.x * w[ii][0];  u1 = xa.x * w[ii][8];
                u2 = xa.x * w[ii][16]; u3 = xa.x * w[ii][24];
                u0 = fmaf(xa.y, w[ii][1],  u0); u1 = fmaf(xa.y, w[ii][9],  u1);
                u2 = fmaf(xa.y, w[ii][17], u2); u3 = fmaf(xa.y, w[ii][25], u3);
                u0 = fmaf(xa.z, w[ii][2],  u0); u1 = fmaf(xa.z, w[ii][10], u1);
                u2 = fmaf(xa.z, w[ii][18], u2); u3 = fmaf(xa.z, w[ii][26], u3);
                u0 = fmaf(xa.w, w[ii][3],  u0); u1 = fmaf(xa.w, w[ii][11], u1);
                u2 = fmaf(xa.w, w[ii][19], u2); u3 = fmaf(xa.w, w[ii][27], u3);
                u0 = fmaf(xb.x, w[ii][4],  u0); u1 = fmaf(xb.x, w[ii][12], u1);
                u2 = fmaf(xb.x, w[ii][20], u2); u3 = fmaf(xb.x, w[ii][28], u3);
                u0 = fmaf(xb.y, w[ii][5],  u0); u1 = fmaf(xb.y, w[ii][13], u1);
                u2 = fmaf(xb.y, w[ii][21], u2); u3 = fmaf(xb.y, w[ii][29], u3);
                u0 = fmaf(xb.z, w[ii][6],  u0); u1 = fmaf(xb.z, w[ii][14], u1);
                u2 = fmaf(xb.z, w[ii][22], u2); u3 = fmaf(xb.z, w[ii][30], u3);
                u0 = fmaf(xb.w, w[ii][7],  u0); u1 = fmaf(xb.w, w[ii][15], u1);
                u2 = fmaf(xb.w, w[ii][23], u2); u3 = fmaf(xb.w, w[ii][31], u3);
                float cw;
                if (USEV == 0) {
                    cw = 1.0f / 16.0f;
                } else {
                    float ag = u0*va.x + u1*va.y + u2*va.z + u3*va.w;
                    ag += __shfl_xor(ag, 1);
                    ag += __shfl_xor(ag, 2);
                    const float blog = 4096.0f * ag;
                    float m = blog;
                    m = fmaxf(m, __shfl_xor(m, 4));
                    m = fmaxf(m, __shfl_xor(m, 8));
                    m = fmaxf(m, __shfl_xor(m, 16));
                    m = fmaxf(m, __shfl_xor(m, 32));
                    const float e = __expf(blog - m);
                    float sum = e;
                    sum += __shfl_xor(sum, 4);
                    sum += __shfl_xor(sum, 8);
                    sum += __shfl_xor(sum, 16);
                    sum += __shfl_xor(sum, 32);
                    cw = __fdividef(e, sum);
                }
                sl[nb][0] = fmaf(cw, u0, sl[nb][0]);
                sl[nb][1] = fmaf(cw, u1, sl[nb][1]);
                sl[nb][2] = fmaf(cw, u2, sl[nb][2]);
                sl[nb][3] = fmaf(cw, u3, sl[nb][3]);
            }
        }
#pragma unroll
        for (int nb = 0; nb < 4; ++nb)
            *(float4*)&lds[wu][nb][lane * 4] =
                make_float4(sl[nb][0], sl[nb][1], sl[nb][2], sl[nb][3]);
        __syncthreads();
        if (tid < 256) {
            const int bsel = tid >> 6;
            const int ad4  = (tid & 63) * 4;
            float4 acc = make_float4(0.f, 0.f, 0.f, 0.f);
#pragma unroll
            for (int wv = 0; wv < 8; ++wv) {
                const float4 f = *(const float4*)&lds[wv][bsel][ad4];
                acc.x += f.x; acc.y += f.y; acc.z += f.z; acc.w += f.w;
            }
            float* dst = srep + (size_t)(b0 + ph * 4 + bsel) * 256 + ad4;
            unsafeAtomicAdd(dst + 0, acc.x);
            unsafeAtomicAdd(dst + 1, acc.y);
            unsafeAtomicAdd(dst + 2, acc.z);
            unsafeAtomicAdd(dst + 3, acc.w);
        }
        __syncthreads();
    }
}

template<int ADDP, int ZERO>
__global__ void legacy_squash(float* __restrict__ srep, int n_rep,
                              float* __restrict__ vout, const float* __restrict__ vprev)
{
    const int t = (int)blockIdx.x * 256 + (int)threadIdx.x;
    float4 f0 = make_float4(0.f,0.f,0.f,0.f), f1 = f0, f2 = f0, f3 = f0;
    for (int r = 0; r < n_rep; ++r) {
        float* sp = srep + (size_t)r * 65536 + (size_t)t * 16;
        const float4 a0 = *(const float4*)(sp + 0);
        const float4 a1 = *(const float4*)(sp + 4);
        const float4 a2 = *(const float4*)(sp + 8);
        const float4 a3 = *(const float4*)(sp + 12);
        f0.x+=a0.x; f0.y+=a0.y; f0.z+=a0.z; f0.w+=a0.w;
        f1.x+=a1.x; f1.y+=a1.y; f1.z+=a1.z; f1.w+=a1.w;
        f2.x+=a2.x; f2.y+=a2.y; f2.z+=a2.z; f2.w+=a2.w;
        f3.x+=a3.x; f3.y+=a3.y; f3.z+=a3.z; f3.w+=a3.w;
        if (ZERO) {
            const float4 z = make_float4(0.f,0.f,0.f,0.f);
            *(float4*)(sp+0)=z; *(float4*)(sp+4)=z; *(float4*)(sp+8)=z; *(float4*)(sp+12)=z;
        }
    }
    float sq = f0.x*f0.x+f0.y*f0.y+f0.z*f0.z+f0.w*f0.w
             + f1.x*f1.x+f1.y*f1.y+f1.z*f1.z+f1.w*f1.w
             + f2.x*f2.x+f2.y*f2.y+f2.z*f2.z+f2.w*f2.w
             + f3.x*f3.x+f3.y*f3.y+f3.z*f3.z+f3.w*f3.w;
    const float scale = sq / ((1.0f + sq) * sqrtf(sq + 1e-7f));
    float4 o0, o1, o2, o3;
    o0.x=f0.x*scale; o0.y=f0.y*scale; o0.z=f0.z*scale; o0.w=f0.w*scale;
    o1.x=f1.x*scale; o1.y=f1.y*scale; o1.z=f1.z*scale; o1.w=f1.w*scale;
    o2.x=f2.x*scale; o2.y=f2.y*scale; o2.z=f2.z*scale; o2.w=f2.w*scale;
    o3.x=f3.x*scale; o3.y=f3.y*scale; o3.z=f3.z*scale; o3.w=f3.w*scale;
    if (ADDP) {
        const float* pp = vprev + (size_t)t * 16;
        const float4 p0 = *(const float4*)(pp + 0);
        const float4 p1 = *(const float4*)(pp + 4);
        const float4 p2 = *(const float4*)(pp + 8);
        const float4 p3 = *(const float4*)(pp + 12);
        o0.x+=p0.x; o0.y+=p0.y; o0.z+=p0.z; o0.w+=p0.w;
        o1.x+=p1.x; o1.y+=p1.y; o1.z+=p1.z; o1.w+=p1.w;
        o2.x+=p2.x; o2.y+=p2.y; o2.z+=p2.z; o2.w+=p2.w;
        o3.x+=p3.x; o3.y+=p3.y; o3.z+=p3.z; o3.w+=p3.w;
    }
    float* vp = vout + (size_t)t * 16;
    *(float4*)(vp+0)=o0; *(float4*)(vp+4)=o1; *(float4*)(vp+8)=o2; *(float4*)(vp+12)=o3;
}

__global__ void legacy_zero(float* __restrict__ p)
{
    *(float4*)(p + ((size_t)blockIdx.x * 256 + threadIdx.x) * 4) =
        make_float4(0.f, 0.f, 0.f, 0.f);
}

extern "C" void kernel_launch(void* const* d_in, const int* in_sizes, int n_in,
                              void* d_out, int out_size, void* d_ws, size_t ws_size,
                              hipStream_t stream)
{
    const float* x = (const float*)d_in[0];   // [256, 4096, 8]
    const float* W = (const float*)d_in[1];   // [16, 4096, 16, 8]
    float* out = (float*)d_out;               // [256, 16, 16]

    // fp16 partials: 1024 tiles x 16384 u32 = 64 MiB
    const size_t need16 = (size_t)1024 * 16384 * 4 + 2 * 65536 * 4;

    if (ws_size >= need16) {
        u32*  part = (u32*)d_ws;
        float* v1  = (float*)((char*)d_ws + (size_t)1024 * 16384 * 4);
        float* vs  = v1 + 65536;
        caps_pass_part<0><<<1024, 512, 0, stream>>>(x, W, nullptr, part);
        caps_squash_part<0><<<128, 256, 0, stream>>>(part, v1, nullptr);
        caps_pass_part<1><<<1024, 512, 0, stream>>>(x, W, v1, part);
        caps_squash_part<1><<<128, 256, 0, stream>>>(part, vs, v1);
        caps_pass_part<1><<<1024, 512, 0, stream>>>(x, W, vs, part);
        caps_squash_part<0><<<128, 256, 0, stream>>>(part, out, nullptr);
    } else {
        int R = 1;
        if (ws_size >= (size_t)(8 + 2) * 65536 * 4) R = 8;
        else if (ws_size >= (size_t)(2 + 2) * 65536 * 4) R = 2;
        float* srep = (float*)d_ws;
        float* v1   = srep + (size_t)R * 65536;
        float* vs   = v1 + 65536;
        legacy_zero<<<R * 64, 256, 0, stream>>>(srep);
        legacy_pass<0><<<256, 512, 0, stream>>>(x, W, nullptr, srep, R);
        legacy_squash<0, 1><<<16, 256, 0, stream>>>(srep, R, v1, nullptr);
        legacy_pass<1><<<256, 512, 0, stream>>>(x, W, v1, srep, R);
        legacy_squash<1, 1><<<16, 256, 0, stream>>>(srep, R, vs, v1);
        legacy_pass<1><<<256, 512, 0, stream>>>(x, W, vs, srep, R);
        legacy_squash<0, 0><<<16, 256, 0, stream>>>(srep, R, out, nullptr);
    }
}

// Round 19
// 421.567 us; speedup vs baseline: 1.2194x; 1.1805x over previous
//
#include <hip/hip_runtime.h>

#define IC 4096
typedef unsigned short u16;
typedef unsigned int   u32;
typedef __fp16 h2 __attribute__((ext_vector_type(2)));   // cvt_pkrtz return type

static __device__ __forceinline__ u32 pack_rtz(float a, float b) {
    h2 h = __builtin_amdgcn_cvt_pkrtz(a, b);   // v_cvt_pkrtz_f16_f32
    u32 u; __builtin_memcpy(&u, &h, 4); return u;
}
static __device__ __forceinline__ float h2lo(u32 r) {
    h2 h; __builtin_memcpy(&h, &r, 4); return (float)h.x;
}
static __device__ __forceinline__ float h2hi(u32 r) {
    h2 h; __builtin_memcpy(&h, &r, 4); return (float)h.y;
}

// Barrier draining only lgkmcnt (r16: proven safe & neutral).
static __device__ __forceinline__ void barrier_lgkm() {
    asm volatile("s_waitcnt lgkmcnt(0)\n\ts_barrier" ::: "memory");
}

// DPP lane permute on the VALU pipe (NOT ds_bpermute/DS pipe).
// CTRL: 0xB1 = quad_perm{1,0,3,2} (xor1), 0x4E = quad_perm{2,3,0,1} (xor2),
// 0x124 = row_ror:4, 0x128 = row_ror:8 (row = 16 lanes).
template<int CTRL>
static __device__ __forceinline__ float dppf(float x) {
    return __int_as_float(__builtin_amdgcn_update_dpp(
        0, __float_as_int(x), CTRL, 0xF, 0xF, true));
}

// ---------------- primary path: DPP softmax + linear reduce ----------
// r18 post-mortem: DPP softmax was a real win (200->184us) but the permuted
// reduce-gather introduced 2.5e7 LDS bank-conflict cycles (~41us/CU-pass).
// Fix: reduce thread m reads LDS LINEARLY at float2 offset m*2 (r13's
// measured-conflict-free pattern) and stores part column m (coalesced);
// the (a,p)->m permutation moves into squash's index math (one-time).
// part column m holds (capsule a, d-pair p) with m = (p>>1)*32 + a*2 + (p&1).
template<int USEV>
__global__ __launch_bounds__(512)
void caps_pass_part(const float* __restrict__ x, const float* __restrict__ W,
                    const float* __restrict__ vprev, u32* __restrict__ part)
{
    __shared__ float lds[8][4][256];
    const int tid  = threadIdx.x;
    const int wu   = __builtin_amdgcn_readfirstlane(tid >> 6);  // wave 0..7
    const int lane = tid & 63;
    const int a    = lane & 15;   // capsule 0..15  (row-of-16 position)
    const int dq   = lane >> 4;   // d-quad 0..3: lane owns d = dq*4..dq*4+3
    const int ib   = (int)blockIdx.x & 511;   // i-chunk
    const int bh   = (int)blockIdx.x >> 9;    // b-half
    const int i    = ib * 8 + wu;             // this wave's i

    float w[32];
    {
        const float* wp = W + ((size_t)a * IC + i) * 128 + dq * 32;
#pragma unroll
        for (int q = 0; q < 8; ++q) {
            const float4 f = *(const float4*)(wp + q * 4);
            w[q*4+0] = f.x; w[q*4+1] = f.y; w[q*4+2] = f.z; w[q*4+3] = f.w;
        }
    }
#pragma unroll
    for (int k = 0; k < 32; ++k) asm volatile("" : "+v"(w[k]));  // no remat

    const int b0 = bh * 128;
    const float SM_SCALE = 4096.0f * 1.44269504088896f;  // logits in log2 units

    for (int ph = 0; ph < 32; ++ph) {
        // prefetch all 4 b's inputs (independent; x is wave-uniform)
        float4 xa[4], xb[4], va[4];
#pragma unroll
        for (int nb = 0; nb < 4; ++nb) {
            const int b = b0 + ph * 4 + nb;
            const float* xp = x + ((size_t)b * IC + i) * 8;
            xa[nb] = *(const float4*)(xp);
            xb[nb] = *(const float4*)(xp + 4);
            if (USEV)
                va[nb] = *(const float4*)(vprev + (((size_t)b * 16 + a) * 16 + dq * 4));
        }
#pragma unroll
        for (int nb = 0; nb < 4; ++nb) {
            float u0, u1, u2, u3;
            u0 = xa[nb].x * w[0];
            u1 = xa[nb].x * w[8];
            u2 = xa[nb].x * w[16];
            u3 = xa[nb].x * w[24];
            u0 = fmaf(xa[nb].y, w[1],  u0); u1 = fmaf(xa[nb].y, w[9],  u1);
            u2 = fmaf(xa[nb].y, w[17], u2); u3 = fmaf(xa[nb].y, w[25], u3);
            u0 = fmaf(xa[nb].z, w[2],  u0); u1 = fmaf(xa[nb].z, w[10], u1);
            u2 = fmaf(xa[nb].z, w[18], u2); u3 = fmaf(xa[nb].z, w[26], u3);
            u0 = fmaf(xa[nb].w, w[3],  u0); u1 = fmaf(xa[nb].w, w[11], u1);
            u2 = fmaf(xa[nb].w, w[19], u2); u3 = fmaf(xa[nb].w, w[27], u3);
            u0 = fmaf(xb[nb].x, w[4],  u0); u1 = fmaf(xb[nb].x, w[12], u1);
            u2 = fmaf(xb[nb].x, w[20], u2); u3 = fmaf(xb[nb].x, w[28], u3);
            u0 = fmaf(xb[nb].y, w[5],  u0); u1 = fmaf(xb[nb].y, w[13], u1);
            u2 = fmaf(xb[nb].y, w[21], u2); u3 = fmaf(xb[nb].y, w[29], u3);
            u0 = fmaf(xb[nb].z, w[6],  u0); u1 = fmaf(xb[nb].z, w[14], u1);
            u2 = fmaf(xb[nb].z, w[22], u2); u3 = fmaf(xb[nb].z, w[30], u3);
            u0 = fmaf(xb[nb].w, w[7],  u0); u1 = fmaf(xb[nb].w, w[15], u1);
            u2 = fmaf(xb[nb].w, w[23], u2); u3 = fmaf(xb[nb].w, w[31], u3);
            float cw;
            if (USEV == 0) {
                cw = 1.0f / 16.0f;
            } else {
                // agree = u . vprev; combine the 4 d-quads (lanes a, a+16,
                // a+32, a+48) -- the only remaining DS ops (2 vs 10).
                float ag = u0 * va[nb].x + u1 * va[nb].y
                         + u2 * va[nb].z + u3 * va[nb].w;
                ag += __shfl_xor(ag, 16);
                ag += __shfl_xor(ag, 32);
                const float blog2 = SM_SCALE * ag;
                // softmax over the 16 capsules = reduce within the 16-lane
                // row, entirely on VALU DPP (r18: -8% vs ds_bpermute chain).
                float m = blog2;
                m = fmaxf(m, dppf<0xB1>(m));    // quad_perm xor1
                m = fmaxf(m, dppf<0x4E>(m));    // quad_perm xor2
                m = fmaxf(m, dppf<0x124>(m));   // row_ror:4
                m = fmaxf(m, dppf<0x128>(m));   // row_ror:8
                const float e = __builtin_amdgcn_exp2f(blog2 - m);
                float sum = e;
                sum += dppf<0xB1>(sum);
                sum += dppf<0x4E>(sum);
                sum += dppf<0x124>(sum);
                sum += dppf<0x128>(sum);
                cw = __fdividef(e, sum);
            }
            // linear per-lane LDS write (b128, conflict-free); element order:
            // float index = dq*64 + a*4 + j  (j = d within the quad).
            *(float4*)&lds[wu][nb][lane * 4] =
                make_float4(cw * u0, cw * u1, cw * u2, cw * u3);
        }
        barrier_lgkm();
        // reduce: ALL 512 threads; thread m = tid&127 reads LDS float2 at
        // m*2 (LINEAR -> conflict-free, r13-proven) and stores part column m
        // (coalesced). Column m holds (a = (m>>1)&15, p = (m>>5)*2 + (m&1)).
        {
            const int nb = tid >> 7;      // 0..3
            const int m  = tid & 127;     // linear float2 / output column
            float s0 = 0.f, s1 = 0.f;
#pragma unroll
            for (int wv = 0; wv < 8; ++wv) {
                const float2 f = *(const float2*)&lds[wv][nb][m * 2];
                s0 += f.x; s1 += f.y;
            }
            part[(size_t)blockIdx.x * 16384 + (size_t)(ph * 4 + nb) * 128 + m] =
                pack_rtz(s0, s1);
        }
        barrier_lgkm();
    }
}

// Fused 512-deep partial reduction + squash. Thread = (b, r = a*8 + dpair):
// the (a,p) -> m layout permutation from the pass is inverted here (index
// math only; reads stay within the same 512B row -> L1-absorbed).
template<int ADDP>
__global__ __launch_bounds__(256)
void caps_squash_part(const u32* __restrict__ part, float* __restrict__ vout,
                      const float* __restrict__ vprev)
{
    const int gt = (int)blockIdx.x * 256 + (int)threadIdx.x;  // 0..32767
    const int b  = gt >> 7;
    const int r  = gt & 127;                                  // a*8 + dpair
    const int a  = r >> 3;
    const int p  = r & 7;
    const int m  = (p >> 1) * 32 + a * 2 + (p & 1);           // part column
    const int h  = b >> 7;                                    // b-half
    const int lb = b & 127;                                   // local b in tile
    const u32* pp = part + ((size_t)h * 512) * 16384 + (size_t)lb * 128 + m;
    float f0 = 0.f, f1 = 0.f;
#pragma unroll 8
    for (int ic = 0; ic < 512; ++ic) {
        const u32 raw = pp[(size_t)ic * 16384];
        f0 += h2lo(raw);
        f1 += h2hi(raw);
    }
    float sq = f0 * f0 + f1 * f1;
    sq += __shfl_xor(sq, 1);
    sq += __shfl_xor(sq, 2);
    sq += __shfl_xor(sq, 4);
    const float scale = sq / ((1.0f + sq) * sqrtf(sq + 1e-7f));
    float o0 = f0 * scale, o1 = f1 * scale;
    if (ADDP) {
        const float2 pv = *(const float2*)(vprev + (size_t)b * 256 + r * 2);
        o0 += pv.x; o1 += pv.y;
    }
    *(float2*)(vout + (size_t)b * 256 + r * 2) = make_float2(o0, o1);
}

// ---------------- legacy fallback (round-4, known-good) ----------------
template<int USEV>
__global__ __launch_bounds__(512)
void legacy_pass(const float* __restrict__ x, const float* __restrict__ W,
                 const float* __restrict__ vprev, float* __restrict__ s_rep,
                 int n_rep)
{
    __shared__ float lds[8][4][256];
    const int tid  = threadIdx.x;
    const int wu   = __builtin_amdgcn_readfirstlane(tid >> 6);
    const int lane = tid & 63;
    const int a    = lane >> 2;
    const int dq   = lane & 3;
    const int ichunk = (int)blockIdx.x >> 1;
    const int bhalf  = (int)blockIdx.x & 1;
    const int i0 = ichunk * 32 + wu * 4;
    const int rep = (int)blockIdx.x & (n_rep - 1);
    float* srep = s_rep + (size_t)rep * 65536;

    float w[4][32];
#pragma unroll
    for (int ii = 0; ii < 4; ++ii) {
        const float* wp = W + ((size_t)a * IC + (size_t)(i0 + ii)) * 128 + dq * 32;
#pragma unroll
        for (int q = 0; q < 8; ++q) {
            const float4 f = *(const float4*)(wp + q * 4);
            w[ii][q*4+0]=f.x; w[ii][q*4+1]=f.y; w[ii][q*4+2]=f.z; w[ii][q*4+3]=f.w;
        }
    }
#pragma unroll
    for (int ii = 0; ii < 4; ++ii)
#pragma unroll
        for (int k = 0; k < 32; ++k) asm volatile("" : "+v"(w[ii][k]));

    const int b0 = bhalf * 128;
    for (int ph = 0; ph < 32; ++ph) {
        float sl[4][4];
#pragma unroll
        for (int nb = 0; nb < 4; ++nb) {
            sl[nb][0]=0.f; sl[nb][1]=0.f; sl[nb][2]=0.f; sl[nb][3]=0.f;
            const int b = b0 + ph * 4 + nb;
            float4 va;
            if (USEV)
                va = *(const float4*)(vprev + (((size_t)b * 16 + a) * 16 + dq * 4));
#pragma unroll
            for (int ii = 0; ii < 4; ++ii) {
                const float* xp = x + ((size_t)b * IC + (size_t)(i0 + ii)) * 8;
                const float4 xa = *(const float4*)(xp);
                const float4 xb = *(const float4*)(xp + 4);
                float u0, u1, u2, u3;
                u0 = xa.x * w[ii][0];  u1 = xa.x * w[ii][8];
                u2 = xa.x * w[ii][16]; u3 = xa.x * w[ii][24];
                u0 = fmaf(xa.y, w[ii][1],  u0); u1 = fmaf(xa.y, w[ii][9],  u1);
                u2 = fmaf(xa.y, w[ii][17], u2); u3 = fmaf(xa.y, w[ii][25], u3);
                u0 = fmaf(xa.z, w[ii][2],  u0); u1 = fmaf(xa.z, w[ii][10], u1);
                u2 = fmaf(xa.z, w[ii][18], u2); u3 = fmaf(xa.z, w[ii][26], u3);
                u0 = fmaf(xa.w, w[ii][3],  u0); u1 = fmaf(xa.w, w[ii][11], u1);
                u2 = fmaf(xa.w, w[ii][19], u2); u3 = fmaf(xa.w, w[ii][27], u3);
                u0 = fmaf(xb.x, w[ii][4],  u0); u1 = fmaf(xb.x, w[ii][12], u1);
                u2 = fmaf(xb.x, w[ii][20], u2); u3 = fmaf(xb.x, w[ii][28], u3);
                u0 = fmaf(xb.y, w[ii][5],  u0); u1 = fmaf(xb.y, w[ii][13], u1);
                u2 = fmaf(xb.y, w[ii][21], u2); u3 = fmaf(xb.y, w[ii][29], u3);
                u0 = fmaf(xb.z, w[ii][6],  u0); u1 = fmaf(xb.z, w[ii][14], u1);
                u2 = fmaf(xb.z, w[ii][22], u2); u3 = fmaf(xb.z, w[ii][30], u3);
                u0 = fmaf(xb.w, w[ii][7],  u0); u1 = fmaf(xb.w, w[ii][15], u1);
                u2 = fmaf(xb.w, w[ii][23], u2); u3 = fmaf(xb.w, w[ii][31], u3);
                float cw;
                if (USEV == 0) {
                    cw = 1.0f / 16.0f;
                } else {
                    float ag = u0*va.x + u1*va.y + u2*va.z + u3*va.w;
                    ag += __shfl_xor(ag, 1);
                    ag += __shfl_xor(ag, 2);
                    const float blog = 4096.0f * ag;
                    float m = blog;
                    m = fmaxf(m, __shfl_xor(m, 4));
                    m = fmaxf(m, __shfl_xor(m, 8));
                    m = fmaxf(m, __shfl_xor(m, 16));
                    m = fmaxf(m, __shfl_xor(m, 32));
                    const float e = __expf(blog - m);
                    float sum = e;
                    sum += __shfl_xor(sum, 4);
                    sum += __shfl_xor(sum, 8);
                    sum += __shfl_xor(sum, 16);
                    sum += __shfl_xor(sum, 32);
                    cw = __fdividef(e, sum);
                }
                sl[nb][0] = fmaf(cw, u0, sl[nb][0]);
                sl[nb][1] = fmaf(cw, u1, sl[nb][1]);
                sl[nb][2] = fmaf(cw, u2, sl[nb][2]);
                sl[nb][3] = fmaf(cw, u3, sl[nb][3]);
            }
        }
#pragma unroll
        for (int nb = 0; nb < 4; ++nb)
            *(float4*)&lds[wu][nb][lane * 4] =
                make_float4(sl[nb][0], sl[nb][1], sl[nb][2], sl[nb][3]);
        __syncthreads();
        if (tid < 256) {
            const int bsel = tid >> 6;
            const int ad4  = (tid & 63) * 4;
            float4 acc = make_float4(0.f, 0.f, 0.f, 0.f);
#pragma unroll
            for (int wv = 0; wv < 8; ++wv) {
                const float4 f = *(const float4*)&lds[wv][bsel][ad4];
                acc.x += f.x; acc.y += f.y; acc.z += f.z; acc.w += f.w;
            }
            float* dst = srep + (size_t)(b0 + ph * 4 + bsel) * 256 + ad4;
            unsafeAtomicAdd(dst + 0, acc.x);
            unsafeAtomicAdd(dst + 1, acc.y);
            unsafeAtomicAdd(dst + 2, acc.z);
            unsafeAtomicAdd(dst + 3, acc.w);
        }
        __syncthreads();
    }
}

template<int ADDP, int ZERO>
__global__ void legacy_squash(float* __restrict__ srep, int n_rep,
                              float* __restrict__ vout, const float* __restrict__ vprev)
{
    const int t = (int)blockIdx.x * 256 + (int)threadIdx.x;
    float4 f0 = make_float4(0.f,0.f,0.f,0.f), f1 = f0, f2 = f0, f3 = f0;
    for (int r = 0; r < n_rep; ++r) {
        float* sp = srep + (size_t)r * 65536 + (size_t)t * 16;
        const float4 a0 = *(const float4*)(sp + 0);
        const float4 a1 = *(const float4*)(sp + 4);
        const float4 a2 = *(const float4*)(sp + 8);
        const float4 a3 = *(const float4*)(sp + 12);
        f0.x+=a0.x; f0.y+=a0.y; f0.z+=a0.z; f0.w+=a0.w;
        f1.x+=a1.x; f1.y+=a1.y; f1.z+=a1.z; f1.w+=a1.w;
        f2.x+=a2.x; f2.y+=a2.y; f2.z+=a2.z; f2.w+=a2.w;
        f3.x+=a3.x; f3.y+=a3.y; f3.z+=a3.z; f3.w+=a3.w;
        if (ZERO) {
            const float4 z = make_float4(0.f,0.f,0.f,0.f);
            *(float4*)(sp+0)=z; *(float4*)(sp+4)=z; *(float4*)(sp+8)=z; *(float4*)(sp+12)=z;
        }
    }
    float sq = f0.x*f0.x+f0.y*f0.y+f0.z*f0.z+f0.w*f0.w
             + f1.x*f1.x+f1.y*f1.y+f1.z*f1.z+f1.w*f1.w
             + f2.x*f2.x+f2.y*f2.y+f2.z*f2.z+f2.w*f2.w
             + f3.x*f3.x+f3.y*f3.y+f3.z*f3.z+f3.w*f3.w;
    const float scale = sq / ((1.0f + sq) * sqrtf(sq + 1e-7f));
    float4 o0, o1, o2, o3;
    o0.x=f0.x*scale; o0.y=f0.y*scale; o0.z=f0.z*scale; o0.w=f0.w*scale;
    o1.x=f1.x*scale; o1.y=f1.y*scale; o1.z=f1.z*scale; o1.w=f1.w*scale;
    o2.x=f2.x*scale; o2.y=f2.y*scale; o2.z=f2.z*scale; o2.w=f2.w*scale;
    o3.x=f3.x*scale; o3.y=f3.y*scale; o3.z=f3.z*scale; o3.w=f3.w*scale;
    if (ADDP) {
        const float* pp = vprev + (size_t)t * 16;
        const float4 p0 = *(const float4*)(pp + 0);
        const float4 p1 = *(const float4*)(pp + 4);
        const float4 p2 = *(const float4*)(pp + 8);
        const float4 p3 = *(const float4*)(pp + 12);
        o0.x+=p0.x; o0.y+=p0.y; o0.z+=p0.z; o0.w+=p0.w;
        o1.x+=p1.x; o1.y+=p1.y; o1.z+=p1.z; o1.w+=p1.w;
        o2.x+=p2.x; o2.y+=p2.y; o2.z+=p2.z; o2.w+=p2.w;
        o3.x+=p3.x; o3.y+=p3.y; o3.z+=p3.z; o3.w+=p3.w;
    }
    float* vp = vout + (size_t)t * 16;
    *(float4*)(vp+0)=o0; *(float4*)(vp+4)=o1; *(float4*)(vp+8)=o2; *(float4*)(vp+12)=o3;
}

__global__ void legacy_zero(float* __restrict__ p)
{
    *(float4*)(p + ((size_t)blockIdx.x * 256 + threadIdx.x) * 4) =
        make_float4(0.f, 0.f, 0.f, 0.f);
}

extern "C" void kernel_launch(void* const* d_in, const int* in_sizes, int n_in,
                              void* d_out, int out_size, void* d_ws, size_t ws_size,
                              hipStream_t stream)
{
    const float* x = (const float*)d_in[0];   // [256, 4096, 8]
    const float* W = (const float*)d_in[1];   // [16, 4096, 16, 8]
    float* out = (float*)d_out;               // [256, 16, 16]

    // fp16 partials: 1024 tiles x 16384 u32 = 64 MiB
    const size_t need16 = (size_t)1024 * 16384 * 4 + 2 * 65536 * 4;

    if (ws_size >= need16) {
        u32*  part = (u32*)d_ws;
        float* v1  = (float*)((char*)d_ws + (size_t)1024 * 16384 * 4);
        float* vs  = v1 + 65536;
        caps_pass_part<0><<<1024, 512, 0, stream>>>(x, W, nullptr, part);
        caps_squash_part<0><<<128, 256, 0, stream>>>(part, v1, nullptr);
        caps_pass_part<1><<<1024, 512, 0, stream>>>(x, W, v1, part);
        caps_squash_part<1><<<128, 256, 0, stream>>>(part, vs, v1);
        caps_pass_part<1><<<1024, 512, 0, stream>>>(x, W, vs, part);
        caps_squash_part<0><<<128, 256, 0, stream>>>(part, out, nullptr);
    } else {
        int R = 1;
        if (ws_size >= (size_t)(8 + 2) * 65536 * 4) R = 8;
        else if (ws_size >= (size_t)(2 + 2) * 65536 * 4) R = 2;
        float* srep = (float*)d_ws;
        float* v1   = srep + (size_t)R * 65536;
        float* vs   = v1 + 65536;
        legacy_zero<<<R * 64, 256, 0, stream>>>(srep);
        legacy_pass<0><<<256, 512, 0, stream>>>(x, W, nullptr, srep, R);
        legacy_squash<0, 1><<<16, 256, 0, stream>>>(srep, R, v1, nullptr);
        legacy_pass<1><<<256, 512, 0, stream>>>(x, W, v1, srep, R);
        legacy_squash<1, 1><<<16, 256, 0, stream>>>(srep, R, vs, v1);
        legacy_pass<1><<<256, 512, 0, stream>>>(x, W, vs, srep, R);
        legacy_squash<0, 0><<<16, 256, 0, stream>>>(srep, R, out, nullptr);
    }
}